// Round 1
// baseline (5758.843 us; speedup 1.0000x reference)
//
#include <hip/hip_runtime.h>

// multiplicativeNoise: dY = G(Y) o dB  (mu_strato == 0 exactly), 100-step RK4,
// per-sample gather at step idx[b] = clip(trunc(100*t[b]), 0, 99).
//
// Per (b,s): A = sum_k G[:,:,k] * dW[s,b,k]  (64x64), then
//   k1 = A y; k2 = A(y+.5k1); k3 = A(y+.5k2); k4 = A(y+k3); y += (k1+2k2+2k3+k4)/6.
//
// Strategy:
//  - counting-sort batch by idx so each 16-elem chunk stops early (mean 50.5 steps).
//  - A-build as MFMA GEMM [16 elems x 64 k] x [64 k x 4096 (i,j)] per step, bf16.
//  - A (bf16) -> LDS; RK4 matvecs on VALU, one wave per element (wave-implicit
//    stage sync), ds_read_b128 row reads (16B-aligned padded strides).

typedef __attribute__((ext_vector_type(8))) short short8;
typedef __attribute__((ext_vector_type(4))) float f32x4;

#define NSTEP 100
#define BATCH 16384
#define NCHUNK 1024            // BATCH / 16
#define ISTR 72                // ushort stride per A-row (64 + 8 pad -> 144B, 16B aligned)
#define ESTR 4616              // ushort stride per elem (64*72 + 8 pad -> 9232B, 16B aligned)

__device__ __forceinline__ unsigned short f2bf(float f) {
  unsigned u = __float_as_uint(f);
  unsigned r = (u + 0x7FFFu + ((u >> 16) & 1u)) >> 16;   // RNE
  return (unsigned short)r;
}
__device__ __forceinline__ float bf2f(unsigned short u) {
  return __uint_as_float(((unsigned)u) << 16);
}

// ---------------- prep kernels ----------------

// G flat index (i*64+j)*64 + k == n*64 + k with n = i*64+j, so the bf16 "G2T[n][k]"
// B-operand table is a pure elementwise cast of G.
__global__ void k_cast(const float* __restrict__ G, unsigned short* __restrict__ g2, int n) {
  int i = blockIdx.x * blockDim.x + threadIdx.x;
  if (i < n) g2[i] = f2bf(G[i]);
}

__global__ void k_idx(const float* __restrict__ t, int* __restrict__ idxb, int* __restrict__ hist) {
  int b = blockIdx.x * blockDim.x + threadIdx.x;
  if (b < BATCH) {
    int ix = (int)truncf(100.0f * t[b]);       // matches jnp.trunc(n*t/T) in fp32
    ix = min(max(ix, 0), NSTEP - 1);
    idxb[b] = ix;
    atomicAdd(&hist[ix], 1);
  }
}

__global__ void k_scan(const int* __restrict__ hist, int* __restrict__ offs) {
  if (threadIdx.x == 0 && blockIdx.x == 0) {
    int run = 0;
    for (int i = 0; i < NSTEP; ++i) { offs[i] = run; run += hist[i]; }
  }
}

__global__ void k_scatter(const int* __restrict__ idxb, const int* __restrict__ offs,
                          int* __restrict__ cur, int* __restrict__ perm) {
  int b = blockIdx.x * blockDim.x + threadIdx.x;
  if (b < BATCH) {
    int ix = idxb[b];
    int pos = offs[ix] + atomicAdd(&cur[ix], 1);
    perm[pos] = b;                              // any within-bin order is valid
  }
}

// ---------------- main kernel ----------------

__device__ __forceinline__ float dot_row(const unsigned short* Ar, const float* vr) {
  float acc = 0.f;
#pragma unroll
  for (int m = 0; m < 8; ++m) {
    short8 av = *(const short8*)(Ar + (m << 3));          // ds_read_b128: 8 bf16 of A row
    float4 va = ((const float4*)vr)[(m << 1)];            // broadcast reads of v
    float4 vb = ((const float4*)vr)[(m << 1) + 1];
    acc = fmaf(bf2f((unsigned short)av[0]), va.x, acc);
    acc = fmaf(bf2f((unsigned short)av[1]), va.y, acc);
    acc = fmaf(bf2f((unsigned short)av[2]), va.z, acc);
    acc = fmaf(bf2f((unsigned short)av[3]), va.w, acc);
    acc = fmaf(bf2f((unsigned short)av[4]), vb.x, acc);
    acc = fmaf(bf2f((unsigned short)av[5]), vb.y, acc);
    acc = fmaf(bf2f((unsigned short)av[6]), vb.z, acc);
    acc = fmaf(bf2f((unsigned short)av[7]), vb.w, acc);
  }
  return acc;
}

__global__ void __launch_bounds__(1024, 1) k_main(
    const float* __restrict__ y0, const float* __restrict__ dW,
    const unsigned short* __restrict__ G2T, const int* __restrict__ perm,
    const int* __restrict__ idxb, float* __restrict__ out)
{
  __shared__ unsigned short Abuf[16 * ESTR];   // 147712 B: A[e][i][j] bf16, padded
  __shared__ unsigned short dwst[1024];        // dw in MFMA A-frag order
  __shared__ float vbuf[16 * 64];              // stage vectors, one row per elem
  __shared__ int meta_b[16], meta_i[16], chunk_max;

  const int t = threadIdx.x;
  const int lane = t & 63;
  const int wave = t >> 6;                     // wave == element for matvec/staging

  // interleave chunk->block mapping so per-CU work (sorted step counts) balances
  int W = blockIdx.x;
  int c = (W & 1) ? (NCHUNK - 1 - (W >> 1)) : (W >> 1);

  if (t < 16) {
    int b = perm[(c << 4) + t];
    meta_b[t] = b;
    meta_i[t] = idxb[b];
  }
  __syncthreads();
  if (t == 0) {
    int m = 0;
    for (int e = 0; e < 16; ++e) m = max(m, meta_i[e]);
    chunk_max = m;
  }
  const int my_b = meta_b[wave];
  const int my_idx = meta_i[wave];
  float y = y0[my_b * 64 + lane];
  vbuf[(wave << 6) + lane] = y;
  __syncthreads();
  const int nsteps = chunk_max + 1;

  const int fl = lane & 15;                    // frag row/col index
  const int fq = lane >> 4;                    // frag quad

  for (int s = 0; s < nsteps; ++s) {
    // ---- stage dW[s] for 16 elems, bf16, A-frag order: dwst[(k>>3)*128 + e*8 + (k&7)]
    {
      float dv = dW[((s * BATCH) + my_b) * 64 + lane];
      dwst[((lane >> 3) << 7) + (wave << 3) + (lane & 7)] = f2bf(dv);
    }
    __syncthreads();
    // ---- A-build: D[e][n] = sum_k dw[e][k] * G[n>>6][n&63][k]; wave w owns tiles w+16*tt
    {
      short8 a0 = *(const short8*)(&dwst[lane << 3]);          // k in [0,32)
      short8 a1 = *(const short8*)(&dwst[512 + (lane << 3)]);  // k in [32,64)
#pragma unroll 4
      for (int tt = 0; tt < 16; ++tt) {
        int nt = wave + (tt << 4);
        int n = (nt << 4) + fl;
        const unsigned short* gp = &G2T[(n << 6) + (fq << 3)];
        short8 b0 = *(const short8*)(gp);
        short8 b1 = *(const short8*)(gp + 32);
        f32x4 acc = {0.f, 0.f, 0.f, 0.f};
        acc = __builtin_amdgcn_mfma_f32_16x16x32_bf16(a0, b0, acc, 0, 0, 0);
        acc = __builtin_amdgcn_mfma_f32_16x16x32_bf16(a1, b1, acc, 0, 0, 0);
        // D: row(elem) = 4*fq + r, col = fl; n = i*64 + j
        int base = (nt >> 2) * ISTR + ((nt & 3) << 4) + fl;
#pragma unroll
        for (int r = 0; r < 4; ++r) {
          int e = (fq << 2) + r;
          Abuf[e * ESTR + base] = f2bf(acc[r]);
        }
      }
    }
    __syncthreads();
    // ---- RK4: wave == elem e, lane == row i.  Stage sync is wave-implicit.
    {
      const unsigned short* Ar = &Abuf[wave * ESTR + lane * ISTR];
      const float* vr = &vbuf[wave << 6];
      float k1 = dot_row(Ar, vr);
      vbuf[(wave << 6) + lane] = fmaf(0.5f, k1, y);
      float k2 = dot_row(Ar, vr);
      vbuf[(wave << 6) + lane] = fmaf(0.5f, k2, y);
      float k3 = dot_row(Ar, vr);
      vbuf[(wave << 6) + lane] = y + k3;
      float k4 = dot_row(Ar, vr);
      y += (k1 + 2.f * k2 + 2.f * k3 + k4) * (1.f / 6.f);
      if (s == my_idx) out[my_b * 64 + lane] = y;
      vbuf[(wave << 6) + lane] = y;            // stage-1 vector for next step
    }
    // no trailing barrier: the staging->build barrier next iteration also
    // guarantees all waves finished reading Abuf/vbuf before they're rewritten.
  }
}

// ---------------- launch ----------------

extern "C" void kernel_launch(void* const* d_in, const int* in_sizes, int n_in,
                              void* d_out, int out_size, void* d_ws, size_t ws_size,
                              hipStream_t stream) {
  const float* y0 = (const float*)d_in[0];
  const float* tv = (const float*)d_in[1];
  const float* G  = (const float*)d_in[2];
  const float* dW = (const float*)d_in[3];
  float* out = (float*)d_out;

  char* w = (char*)d_ws;
  unsigned short* g2 = (unsigned short*)w;          // 512 KB bf16 G table
  int* idxb = (int*)(w + 524288);                   // 64 KB
  int* perm = (int*)(w + 524288 + 65536);           // 64 KB
  int* hist = (int*)(w + 524288 + 131072);          // 128 ints
  int* offs = hist + 128;
  int* cur  = hist + 256;

  hipMemsetAsync(hist, 0, 1536, stream);            // zero hist+offs+cur
  k_cast<<<1024, 256, 0, stream>>>(G, g2, 64 * 64 * 64);
  k_idx<<<64, 256, 0, stream>>>(tv, idxb, hist);
  k_scan<<<1, 64, 0, stream>>>(hist, offs);
  k_scatter<<<64, 256, 0, stream>>>(idxb, offs, cur, perm);
  k_main<<<NCHUNK, 1024, 0, stream>>>(y0, dW, g2, perm, idxb, out);
}